// Round 14
// baseline (557.256 us; speedup 1.0000x reference)
//
#include <hip/hip_runtime.h>
#include <hip/hip_fp16.h>

#define EPSF 1e-5f
#define BKT_SHIFT 9
#define BKT_NODES 512              // nodes per bucket
#define TILE_E 4096                // edges per k_bpart block

typedef _Float16 half2_t __attribute__((ext_vector_type(2)));
typedef _Float16 half4_t __attribute__((ext_vector_type(4)));
typedef _Float16 half8_t __attribute__((ext_vector_type(8)));

__device__ __forceinline__ float elu_f(float x) { return x > 0.f ? x : expm1f(x); }

__device__ __forceinline__ float fdot2f(half2_t a, half2_t b, float c) {
#if __has_builtin(__builtin_amdgcn_fdot2)
    return __builtin_amdgcn_fdot2(a, b, c, false);
#else
    return c + (float)a.x * (float)b.x + (float)a.y * (float)b.y;
#endif
}
__device__ __forceinline__ half2_t bch2(unsigned u) { return __builtin_bit_cast(half2_t, u); }
__device__ __forceinline__ half4_t bch4(uint2 u) { return __builtin_bit_cast(half4_t, u); }
__device__ __forceinline__ half8_t bch8(uint4 u) { return __builtin_bit_cast(half8_t, u); }

__device__ __forceinline__ uint2 f4_to_h4(float4 v) {
    __half2 a = __floats2half2_rn(v.x, v.y);
    __half2 b = __floats2half2_rn(v.z, v.w);
    uint2 u;
    u.x = *reinterpret_cast<unsigned*>(&a);
    u.y = *reinterpret_cast<unsigned*>(&b);
    return u;
}

// ---------------- bucketed CSR build ----------------

__global__ __launch_bounds__(256) void k_zero(int* p, int n) {
    int i = blockIdx.x * 256 + threadIdx.x;
    if (i < n) p[i] = 0;
}

__global__ __launch_bounds__(256) void k_bhist(const int* __restrict__ dst, int* __restrict__ bkt_cnt, int E) {
    __shared__ int h[256];
    int t = threadIdx.x;
    h[t] = 0;
    __syncthreads();
    for (long e = (long)blockIdx.x * 256 + t; e < E; e += (long)gridDim.x * 256)
        atomicAdd(&h[dst[e] >> BKT_SHIFT], 1);
    __syncthreads();
    if (h[t]) atomicAdd(&bkt_cnt[t], h[t]);
}

__global__ __launch_bounds__(256) void k_bscan(const int* __restrict__ bkt_cnt, int* __restrict__ bbase,
                                               int* __restrict__ cursor) {
    __shared__ int sh[256];
    int t = threadIdx.x;
    int v = bkt_cnt[t];
    sh[t] = v;
    __syncthreads();
    for (int off = 1; off < 256; off <<= 1) {
        int add = (t >= off) ? sh[t - off] : 0;
        __syncthreads();
        sh[t] += add;
        __syncthreads();
    }
    int ex = sh[t] - v;
    bbase[t] = ex;
    cursor[t] = ex;
}

// partition edges into bucket-contiguous packed csr_tmp = (d&511)<<18 | src  (src < 2^17)
__global__ __launch_bounds__(256) void k_bpart(const int* __restrict__ src, const int* __restrict__ dst,
                                               int* __restrict__ cursor, unsigned* __restrict__ csr_tmp, int E) {
    __shared__ int hcnt[256];
    __shared__ int gbase[256];
    int t = threadIdx.x;
    long tile0 = (long)blockIdx.x * TILE_E;
    hcnt[t] = 0;
    __syncthreads();
    int d[16], s[16], rk[16];
    #pragma unroll
    for (int j = 0; j < 16; ++j) {
        long e = tile0 + j * 256 + t;
        if (e < E) {
            d[j] = dst[e];
            s[j] = src[e];
            rk[j] = atomicAdd(&hcnt[d[j] >> BKT_SHIFT], 1);
        }
    }
    __syncthreads();
    int c = hcnt[t];
    if (c) gbase[t] = atomicAdd(&cursor[t], c);
    __syncthreads();
    #pragma unroll
    for (int j = 0; j < 16; ++j) {
        long e = tile0 + j * 256 + t;
        if (e < E) {
            unsigned pk = ((unsigned)(d[j] & (BKT_NODES - 1)) << 18) | (unsigned)s[j];
            csr_tmp[gbase[d[j] >> BKT_SHIFT] + rk[j]] = pk;
        }
    }
}

__global__ __launch_bounds__(256) void k_bfine(const unsigned* __restrict__ csr_tmp, const int* __restrict__ bbase,
                                               const int* __restrict__ bkt_cnt, int* __restrict__ cnt,
                                               int* __restrict__ base, float* __restrict__ dinv,
                                               int* __restrict__ csr_s, int N) {
    __shared__ int cnt5[BKT_NODES];
    __shared__ int off5[BKT_NODES];
    __shared__ int sh[256];
    int b = blockIdx.x;
    int t = threadIdx.x;
    int d0 = b << BKT_SHIFT;
    int bb = bbase[b];
    int bc = bkt_cnt[b];
    cnt5[t] = 0;
    cnt5[t + 256] = 0;
    __syncthreads();
    for (int k = t; k < bc; k += 256) atomicAdd(&cnt5[csr_tmp[bb + k] >> 18], 1);
    __syncthreads();
    int v0 = cnt5[2 * t], v1 = cnt5[2 * t + 1];
    int p = v0 + v1;
    sh[t] = p;
    __syncthreads();
    for (int off = 1; off < 256; off <<= 1) {
        int add = (t >= off) ? sh[t - off] : 0;
        __syncthreads();
        sh[t] += add;
        __syncthreads();
    }
    int pre = sh[t] - p;
    off5[2 * t] = pre;
    off5[2 * t + 1] = pre + v0;
    #pragma unroll
    for (int j = 0; j < 2; ++j) {
        int idx = 2 * t + j;
        int i = d0 + idx;
        if (i < N) {
            int c = cnt5[idx];
            base[i] = bb + off5[idx];
            cnt[i] = c;
            dinv[i] = rsqrtf((float)(c + 1));  // +1 self-loop
        }
    }
    __syncthreads();
    for (int k = t; k < bc; k += 256) {
        unsigned e = csr_tmp[bb + k];
        int pos = bb + atomicAdd(&off5[e >> 18], 1);
        csr_s[pos] = (int)(e & 0x3FFFFu);
    }
}

// ---------------- W2/W3 -> half2 k-pair-major (once per launch; fuse kernels stage via uint4) ----------------
__global__ __launch_bounds__(256) void k_wconv(const float* __restrict__ W2, const float* __restrict__ W3,
                                               unsigned* __restrict__ W2h, unsigned* __restrict__ W3h) {
    int t = blockIdx.x * 256 + threadIdx.x;
    if (t < 16 * 64) {
        int p = t >> 6, j = t & 63;
        half2_t w;
        w.x = (_Float16)W2[(2 * p) * 64 + j];
        w.y = (_Float16)W2[(2 * p + 1) * 64 + j];
        W2h[t] = __builtin_bit_cast(unsigned, w);
    }
    if (t < 32 * 128) {
        int p = t >> 7, j = t & 127;
        half2_t w;
        w.x = (_Float16)W3[(2 * p) * 128 + j];
        w.y = (_Float16)W3[(2 * p + 1) * 128 + j];
        W3h[t] = __builtin_bit_cast(unsigned, w);
    }
}

// ---------------- layer-1 gather (fp16 in/out, half4 packed acc, 8-deep, BN+ELU+prescale) ----------------
__global__ __launch_bounds__(256) void k_gath1(const int* __restrict__ base, const int* __restrict__ cnt,
                                               const int* __restrict__ csr_s, const float* __restrict__ dinv,
                                               const uint2* __restrict__ Xh,   // P1: 8 uint2/row
                                               const float* __restrict__ b, const float* __restrict__ g,
                                               const float* __restrict__ be, const float* __restrict__ rm,
                                               const float* __restrict__ rv, uint2* __restrict__ out, int n) {
    int lane = threadIdx.x & 7, nl = threadIdx.x >> 3;
    long i = (long)blockIdx.x * 32 + nl;
    if (i >= n) return;
    int k = base[i], kend = k + cnt[i];
    float di = dinv[i];
    half4_t a0 = {0, 0, 0, 0}, a1 = a0, a2 = a0, a3 = a0, a4 = a0, a5 = a0, a6 = a0, a7 = a0;
    for (; k + 7 < kend; k += 8) {
        int s0 = csr_s[k], s1 = csr_s[k + 1], s2 = csr_s[k + 2], s3 = csr_s[k + 3];
        int s4 = csr_s[k + 4], s5 = csr_s[k + 5], s6 = csr_s[k + 6], s7 = csr_s[k + 7];
        a0 += bch4(Xh[(long)s0 * 8 + lane]);
        a1 += bch4(Xh[(long)s1 * 8 + lane]);
        a2 += bch4(Xh[(long)s2 * 8 + lane]);
        a3 += bch4(Xh[(long)s3 * 8 + lane]);
        a4 += bch4(Xh[(long)s4 * 8 + lane]);
        a5 += bch4(Xh[(long)s5 * 8 + lane]);
        a6 += bch4(Xh[(long)s6 * 8 + lane]);
        a7 += bch4(Xh[(long)s7 * 8 + lane]);
    }
    for (; k + 1 < kend; k += 2) {
        int s0 = csr_s[k], s1 = csr_s[k + 1];
        a0 += bch4(Xh[(long)s0 * 8 + lane]);
        a1 += bch4(Xh[(long)s1 * 8 + lane]);
    }
    if (k < kend) a0 += bch4(Xh[(long)csr_s[k] * 8 + lane]);
    half4_t s4v = (((a0 + a1) + (a2 + a3)) + ((a4 + a5) + (a6 + a7))) + bch4(Xh[i * 8 + lane]);
    float4 o;
    o.x = di * (float)s4v[0];
    o.y = di * (float)s4v[1];
    o.z = di * (float)s4v[2];
    o.w = di * (float)s4v[3];
    float4 bb = reinterpret_cast<const float4*>(b)[lane];
    float4 gg = reinterpret_cast<const float4*>(g)[lane];
    float4 ee = reinterpret_cast<const float4*>(be)[lane];
    float4 mm = reinterpret_cast<const float4*>(rm)[lane];
    float4 vv = reinterpret_cast<const float4*>(rv)[lane];
    o.x = di * elu_f((o.x + bb.x - mm.x) * rsqrtf(vv.x + EPSF) * gg.x + ee.x);
    o.y = di * elu_f((o.y + bb.y - mm.y) * rsqrtf(vv.y + EPSF) * gg.y + ee.y);
    o.z = di * elu_f((o.z + bb.z - mm.z) * rsqrtf(vv.z + EPSF) * gg.z + ee.z);
    o.w = di * elu_f((o.w + bb.w - mm.w) * rsqrtf(vv.w + EPSF) * gg.w + ee.w);
    out[i * 8 + lane] = f4_to_h4(o);
}

// scalar gather for layer 4 (y pre-scaled by dinv) + bias + sigmoid(elu(.)) -> d_out
__global__ __launch_bounds__(256) void k_gather1_final(const int* __restrict__ base, const int* __restrict__ cnt,
                                                       const int* __restrict__ csr_s,
                                                       const float* __restrict__ dinv, const float* __restrict__ y,
                                                       const float* __restrict__ b4, float* __restrict__ out, int n) {
    int i = blockIdx.x * 256 + threadIdx.x;
    if (i >= n) return;
    int k = base[i];
    int kend = k + cnt[i];
    float di = dinv[i];
    float a0 = 0.f, a1 = 0.f, a2 = 0.f, a3 = 0.f;
    for (; k + 3 < kend; k += 4) {
        a0 += y[csr_s[k]];
        a1 += y[csr_s[k + 1]];
        a2 += y[csr_s[k + 2]];
        a3 += y[csr_s[k + 3]];
    }
    for (; k < kend; ++k) a0 += y[csr_s[k]];
    float v = di * (((a0 + a1) + (a2 + a3)) + y[i]) + b4[0];
    v = elu_f(v);
    out[i] = 1.f / (1.f + expf(-v));
}

// ---------------- f32 register-tiled GEMM (layer 1: f32 x input -> fp16 prescaled) ----------------
template<int DIN, int DOUT>
__global__ __launch_bounds__(256, 4) void k_gemm1(const float* __restrict__ X, const float* __restrict__ W,
                                                  const float* __restrict__ dinv, uint2* __restrict__ Y, int n) {
    constexpr int TR = 4;
    constexpr int FL = DOUT / 4;
    constexpr int RG = 256 / FL;
    constexpr int BR = RG * TR;
    __shared__ float Wl[DIN * DOUT];
    for (int idx = threadIdx.x; idx < DIN * DOUT; idx += 256) Wl[idx] = W[idx];
    __syncthreads();
    const int fl = threadIdx.x % FL;
    const int rg = threadIdx.x / FL;
    const int f0 = fl * 4;
    const long r0 = (long)blockIdx.x * BR + (long)rg * TR;

    float4 z; z.x = z.y = z.z = z.w = 0.f;
    float4 acc[TR];
    #pragma unroll
    for (int r = 0; r < TR; ++r) acc[r] = z;

    #pragma unroll 2
    for (int k0 = 0; k0 < DIN; k0 += 4) {
        float4 xv[TR];
        #pragma unroll
        for (int r = 0; r < TR; ++r) {
            long row = r0 + r;
            xv[r] = (row < n) ? *reinterpret_cast<const float4*>(X + row * DIN + k0) : z;
        }
        #pragma unroll
        for (int kk = 0; kk < 4; ++kk) {
            float4 w4 = *reinterpret_cast<const float4*>(&Wl[(k0 + kk) * DOUT + f0]);
            #pragma unroll
            for (int r = 0; r < TR; ++r) {
                float xs = (kk == 0) ? xv[r].x : (kk == 1) ? xv[r].y : (kk == 2) ? xv[r].z : xv[r].w;
                acc[r].x += xs * w4.x;
                acc[r].y += xs * w4.y;
                acc[r].z += xs * w4.z;
                acc[r].w += xs * w4.w;
            }
        }
    }
    #pragma unroll
    for (int r = 0; r < TR; ++r) {
        long row = r0 + r;
        if (row >= n) continue;
        float dv = dinv[row];
        float4 v = acc[r];
        v.x *= dv; v.y *= dv; v.z *= dv; v.w *= dv;
        Y[row * FL + fl] = f4_to_h4(v);
    }
}

// ---------------- fused gather + fp16 GEMM, layer 2 (32 -> 64), 512 thr / 64 rows ----------------
__global__ __launch_bounds__(512, 8) void k_fuse2(const int* __restrict__ base, const int* __restrict__ cnt,
                                                  const int* __restrict__ csr_s, const float* __restrict__ dinv,
                                                  const uint2* __restrict__ Xh,   // Q1: 8 uint2 per row
                                                  const unsigned* __restrict__ W2h,
                                                  const float* __restrict__ b,
                                                  const float* __restrict__ g, const float* __restrict__ be,
                                                  const float* __restrict__ rm, const float* __restrict__ rv,
                                                  uint2* __restrict__ Y,          // P2: 16 uint2 per row
                                                  int n) {
    __shared__ __align__(16) half2_t Wl2[16 * 64];   // 4 KB, k-pair-major
    __shared__ __align__(16) uint2 T2[64 * 8];       // 4 KB row tile (64 rows x 32 halves)
    __shared__ float Dl[64];
    int t = threadIdx.x;
    {   // stage pre-converted W2h via uint4 (256 uint4)
        const uint4* Wg = reinterpret_cast<const uint4*>(W2h);
        uint4* Wl4 = reinterpret_cast<uint4*>(Wl2);
        if (t < 256) Wl4[t] = Wg[t];
    }
    // Phase A: gather (half4 packed accumulation, 4-deep)
    int lane = t & 7, nl = t >> 3;
    long i = (long)blockIdx.x * 64 + nl;
    float4 z = {0.f, 0.f, 0.f, 0.f};
    float4 o = z;
    float di = 0.f;
    if (i < n) {
        int k = base[i], kend = k + cnt[i];
        di = dinv[i];
        half4_t a0 = {0, 0, 0, 0}, a1 = a0, a2 = a0, a3 = a0;
        for (; k + 3 < kend; k += 4) {
            int s0 = csr_s[k], s1 = csr_s[k + 1], s2 = csr_s[k + 2], s3 = csr_s[k + 3];
            a0 += bch4(Xh[(long)s0 * 8 + lane]);
            a1 += bch4(Xh[(long)s1 * 8 + lane]);
            a2 += bch4(Xh[(long)s2 * 8 + lane]);
            a3 += bch4(Xh[(long)s3 * 8 + lane]);
        }
        for (; k < kend; ++k) a0 += bch4(Xh[(long)csr_s[k] * 8 + lane]);
        half4_t s4 = ((a0 + a1) + (a2 + a3)) + bch4(Xh[i * 8 + lane]);
        o.x = di * (float)s4[0];
        o.y = di * (float)s4[1];
        o.z = di * (float)s4[2];
        o.w = di * (float)s4[3];
    }
    T2[nl * 8 + lane] = f4_to_h4(o);
    if (lane == 0) Dl[nl] = di;
    __syncthreads();

    // Phase B: GEMM. fl covers 4 fouts, rg covers TR=2 rows (32 groups x 2 = 64 rows).
    int fl = t & 15, rg = t >> 4;
    int f0 = fl * 4;
    const uint4* T4 = reinterpret_cast<const uint4*>(T2);  // 4 uint4 per row
    float4 acc0 = z, acc1 = z;
    #pragma unroll
    for (int c = 0; c < 4; ++c) {
        uint4 ra = T4[(rg * 2 + 0) * 4 + c];
        uint4 rb = T4[(rg * 2 + 1) * 4 + c];
        #pragma unroll
        for (int q = 0; q < 4; ++q) {
            uint4 wv = *reinterpret_cast<const uint4*>(&Wl2[(c * 4 + q) * 64 + f0]);
            half2_t w0 = bch2(wv.x), w1 = bch2(wv.y), w2 = bch2(wv.z), w3 = bch2(wv.w);
            unsigned ua = (q == 0) ? ra.x : (q == 1) ? ra.y : (q == 2) ? ra.z : ra.w;
            unsigned ub = (q == 0) ? rb.x : (q == 1) ? rb.y : (q == 2) ? rb.z : rb.w;
            half2_t xa = bch2(ua), xb = bch2(ub);
            acc0.x = fdot2f(xa, w0, acc0.x); acc0.y = fdot2f(xa, w1, acc0.y);
            acc0.z = fdot2f(xa, w2, acc0.z); acc0.w = fdot2f(xa, w3, acc0.w);
            acc1.x = fdot2f(xb, w0, acc1.x); acc1.y = fdot2f(xb, w1, acc1.y);
            acc1.z = fdot2f(xb, w2, acc1.z); acc1.w = fdot2f(xb, w3, acc1.w);
        }
    }
    float4 bias = *reinterpret_cast<const float4*>(b + f0);
    float4 gg = *reinterpret_cast<const float4*>(g + f0);
    float4 ee = *reinterpret_cast<const float4*>(be + f0);
    float4 mm = *reinterpret_cast<const float4*>(rm + f0);
    float4 vv = *reinterpret_cast<const float4*>(rv + f0);
    float4 scale, shift;
    scale.x = gg.x * rsqrtf(vv.x + EPSF); shift.x = ee.x - mm.x * scale.x;
    scale.y = gg.y * rsqrtf(vv.y + EPSF); shift.y = ee.y - mm.y * scale.y;
    scale.z = gg.z * rsqrtf(vv.z + EPSF); shift.z = ee.z - mm.z * scale.z;
    scale.w = gg.w * rsqrtf(vv.w + EPSF); shift.w = ee.w - mm.w * scale.w;
    #pragma unroll
    for (int r = 0; r < 2; ++r) {
        long row = (long)blockIdx.x * 64 + rg * 2 + r;
        if (row >= n) continue;
        float4 v = r ? acc1 : acc0;
        float dv = Dl[rg * 2 + r];
        v.x = dv * elu_f((v.x + bias.x) * scale.x + shift.x);
        v.y = dv * elu_f((v.y + bias.y) * scale.y + shift.y);
        v.z = dv * elu_f((v.z + bias.z) * scale.z + shift.z);
        v.w = dv * elu_f((v.w + bias.w) * scale.w + shift.w);
        Y[row * 16 + fl] = f4_to_h4(v);
    }
}

// ---------------- fused gather + fp16 GEMM + W4-dot, layer 3 (64->128->1), 512 thr / 64 rows ----------------
__global__ __launch_bounds__(512, 8) void k_fuse3(const int* __restrict__ base, const int* __restrict__ cnt,
                                                  const int* __restrict__ csr_s, const float* __restrict__ dinv,
                                                  const uint4* __restrict__ Xh,   // P2: 8 uint4 per row
                                                  const unsigned* __restrict__ W3h,
                                                  const float* __restrict__ b,
                                                  const float* __restrict__ g, const float* __restrict__ be,
                                                  const float* __restrict__ rm, const float* __restrict__ rv,
                                                  const float* __restrict__ W4,
                                                  float* __restrict__ y, int n) {
    __shared__ __align__(16) half2_t Wl2[32 * 128];  // 16 KB, k-pair-major
    __shared__ uint4 T3[64 * 8];                     // 8 KB row tile (64 rows x 64 halves)
    __shared__ float Dl[64];
    int t = threadIdx.x;
    {   // stage pre-converted W3h via uint4 (1024 uint4)
        const uint4* Wg = reinterpret_cast<const uint4*>(W3h);
        uint4* Wl4 = reinterpret_cast<uint4*>(Wl2);
        Wl4[t] = Wg[t];
        Wl4[t + 512] = Wg[t + 512];
    }
    // Phase A: gather (half8 packed accumulation, 4-deep)
    int lane = t & 7, nl = t >> 3;
    long i = (long)blockIdx.x * 64 + nl;
    float4 z = {0.f, 0.f, 0.f, 0.f};
    float4 oLo = z, oHi = z;
    float di = 0.f;
    if (i < n) {
        int k = base[i], kend = k + cnt[i];
        di = dinv[i];
        half8_t a0 = {0, 0, 0, 0, 0, 0, 0, 0}, a1 = a0, a2 = a0, a3 = a0;
        for (; k + 3 < kend; k += 4) {
            int s0 = csr_s[k], s1 = csr_s[k + 1], s2 = csr_s[k + 2], s3 = csr_s[k + 3];
            a0 += bch8(Xh[(long)s0 * 8 + lane]);
            a1 += bch8(Xh[(long)s1 * 8 + lane]);
            a2 += bch8(Xh[(long)s2 * 8 + lane]);
            a3 += bch8(Xh[(long)s3 * 8 + lane]);
        }
        for (; k < kend; ++k) a0 += bch8(Xh[(long)csr_s[k] * 8 + lane]);
        half8_t s8 = ((a0 + a1) + (a2 + a3)) + bch8(Xh[i * 8 + lane]);
        oLo.x = di * (float)s8[0]; oLo.y = di * (float)s8[1];
        oLo.z = di * (float)s8[2]; oLo.w = di * (float)s8[3];
        oHi.x = di * (float)s8[4]; oHi.y = di * (float)s8[5];
        oHi.z = di * (float)s8[6]; oHi.w = di * (float)s8[7];
    }
    uint2 pl = f4_to_h4(oLo), ph = f4_to_h4(oHi);
    uint4 packed; packed.x = pl.x; packed.y = pl.y; packed.z = ph.x; packed.w = ph.y;
    T3[nl * 8 + lane] = packed;
    if (lane == 0) Dl[nl] = di;
    __syncthreads();

    // Phase B: GEMM. fl covers 4 fouts (of 128), rg covers TR=4 rows (16 groups x 4 = 64 rows).
    int fl = t & 31, rg = t >> 5;
    int f0 = fl * 4;
    float4 acc[4] = {z, z, z, z};
    #pragma unroll 2
    for (int c = 0; c < 8; ++c) {
        uint4 rowc[4];
        #pragma unroll
        for (int r = 0; r < 4; ++r) rowc[r] = T3[(rg * 4 + r) * 8 + c];
        #pragma unroll
        for (int q = 0; q < 4; ++q) {
            uint4 wv = *reinterpret_cast<const uint4*>(&Wl2[(c * 4 + q) * 128 + f0]);
            half2_t w0 = bch2(wv.x), w1 = bch2(wv.y), w2 = bch2(wv.z), w3 = bch2(wv.w);
            #pragma unroll
            for (int r = 0; r < 4; ++r) {
                unsigned xu = (q == 0) ? rowc[r].x : (q == 1) ? rowc[r].y : (q == 2) ? rowc[r].z : rowc[r].w;
                half2_t xp = bch2(xu);
                acc[r].x = fdot2f(xp, w0, acc[r].x);
                acc[r].y = fdot2f(xp, w1, acc[r].y);
                acc[r].z = fdot2f(xp, w2, acc[r].z);
                acc[r].w = fdot2f(xp, w3, acc[r].w);
            }
        }
    }
    float4 bias = *reinterpret_cast<const float4*>(b + f0);
    float4 gg = *reinterpret_cast<const float4*>(g + f0);
    float4 ee = *reinterpret_cast<const float4*>(be + f0);
    float4 mm = *reinterpret_cast<const float4*>(rm + f0);
    float4 vv = *reinterpret_cast<const float4*>(rv + f0);
    float4 w4d = *reinterpret_cast<const float4*>(W4 + f0);
    float4 scale, shift;
    scale.x = gg.x * rsqrtf(vv.x + EPSF); shift.x = ee.x - mm.x * scale.x;
    scale.y = gg.y * rsqrtf(vv.y + EPSF); shift.y = ee.y - mm.y * scale.y;
    scale.z = gg.z * rsqrtf(vv.z + EPSF); shift.z = ee.z - mm.z * scale.z;
    scale.w = gg.w * rsqrtf(vv.w + EPSF); shift.w = ee.w - mm.w * scale.w;
    #pragma unroll
    for (int r = 0; r < 4; ++r) {
        long row = (long)blockIdx.x * 64 + rg * 4 + r;
        if (row >= n) continue;
        float4 v = acc[r];
        v.x = elu_f((v.x + bias.x) * scale.x + shift.x);
        v.y = elu_f((v.y + bias.y) * scale.y + shift.y);
        v.z = elu_f((v.z + bias.z) * scale.z + shift.z);
        v.w = elu_f((v.w + bias.w) * scale.w + shift.w);
        float p = v.x * w4d.x + v.y * w4d.y + v.z * w4d.z + v.w * w4d.w;
        #pragma unroll
        for (int m = 1; m < 32; m <<= 1) p += __shfl_xor(p, m, 64);
        if (fl == 0) y[row] = Dl[rg * 4 + r] * p;
    }
}

// ---------------- launch ----------------

extern "C" void kernel_launch(void* const* d_in, const int* in_sizes, int n_in,
                              void* d_out, int out_size, void* d_ws, size_t ws_size,
                              hipStream_t stream) {
    const float* x   = (const float*)d_in[0];
    const int*   edg = (const int*)d_in[1];
    const float* W1 = (const float*)d_in[2];
    const float* b1 = (const float*)d_in[3];
    const float* W2 = (const float*)d_in[4];
    const float* b2 = (const float*)d_in[5];
    const float* W3 = (const float*)d_in[6];
    const float* b3 = (const float*)d_in[7];
    const float* W4 = (const float*)d_in[8];
    const float* b4 = (const float*)d_in[9];
    const float* g1  = (const float*)d_in[10];
    const float* be1 = (const float*)d_in[11];
    const float* rm1 = (const float*)d_in[12];
    const float* rv1 = (const float*)d_in[13];
    const float* g2  = (const float*)d_in[14];
    const float* be2 = (const float*)d_in[15];
    const float* rm2 = (const float*)d_in[16];
    const float* rv2 = (const float*)d_in[17];
    const float* g3  = (const float*)d_in[18];
    const float* be3 = (const float*)d_in[19];
    const float* rm3 = (const float*)d_in[20];
    const float* rv3 = (const float*)d_in[21];
    float* out = (float*)d_out;

    const int N = in_sizes[0] / 64;
    const int E = in_sizes[1] / 2;
    const int* src = edg;
    const int* dst = edg + E;
    const int NB_BKT = (N + BKT_NODES - 1) / BKT_NODES;
    const int NTILES = (E + TILE_E - 1) / TILE_E;

    // workspace layout
    int*      bkt_cnt = (int*)d_ws;                 // 256
    int*      bbase   = bkt_cnt + 256;              // 256
    int*      cursor  = bbase + 256;                // 256
    unsigned* W2h     = (unsigned*)(cursor + 256);  // 1024  (16B-aligned)
    unsigned* W3h     = W2h + 1024;                 // 4096  (16B-aligned)
    int*      cnt     = (int*)(W3h + 4096);         // N
    int*      base    = cnt + N;                    // N
    float*    dinv    = (float*)(base + N);         // N
    int*      csr_s   = (int*)(dinv + N);           // E (permanent: gathers read it)
    float*    featA   = (float*)(csr_s + E);        // N*64 f32 capacity
    float*    featB   = featA + (size_t)N * 64;     // N*64 f32 capacity
    unsigned* csr_tmp = (unsigned*)featA;           // CSR-build-only alias (E uints)

    auto nb = [](long total) { return (int)((total + 255) / 256); };

    // bucketed CSR build + weight conversion
    k_zero<<<1, 256, 0, stream>>>(bkt_cnt, 256);
    k_bhist<<<512, 256, 0, stream>>>(dst, bkt_cnt, E);
    k_wconv<<<16, 256, 0, stream>>>(W2, W3, W2h, W3h);
    k_bscan<<<1, 256, 0, stream>>>(bkt_cnt, bbase, cursor);
    k_bpart<<<NTILES, 256, 0, stream>>>(src, dst, cursor, csr_tmp, E);
    k_bfine<<<NB_BKT, 256, 0, stream>>>(csr_tmp, bbase, bkt_cnt, cnt, base, dinv, csr_s, N);

    // Layer 1 (64->32): f32 GEMM -> P1 fp16 (prescaled); gather+BN+ELU -> Q1 fp16 (prescaled)
    k_gemm1<64, 32><<<(N + 127) / 128, 256, 0, stream>>>(x, W1, dinv, (uint2*)featB, N);
    k_gath1<<<(N + 31) / 32, 256, 0, stream>>>(base, cnt, csr_s, dinv, (const uint2*)featB,
                                               b1, g1, be1, rm1, rv1, (uint2*)featA, N);

    // Layer 2 (32->64): fused gather(Q1) + GEMM + BN + ELU -> P2 fp16 (prescaled)
    k_fuse2<<<(N + 63) / 64, 512, 0, stream>>>(base, cnt, csr_s, dinv, (const uint2*)featA,
                                               W2h, b2, g2, be2, rm2, rv2, (uint2*)featB, N);

    // Layer 3 (64->128->1): fused gather(P2) + GEMM + BN + ELU + dot(W4) (prescaled) -> y f32
    k_fuse3<<<(N + 63) / 64, 512, 0, stream>>>(base, cnt, csr_s, dinv, (const uint4*)featB,
                                               W3h, b3, g3, be3, rm3, rv3, W4, featA, N);

    // Layer 4 (128->1): scalar gather + bias + sigmoid(elu(.)) -> d_out
    k_gather1_final<<<nb(N), 256, 0, stream>>>(base, cnt, csr_s, dinv, featA, b4, out, N);
}